// Round 1
// baseline (343.799 us; speedup 1.0000x reference)
//
#include <hip/hip_runtime.h>
#include <math.h>

#define B 128
#define M 32
#define P 8732
#define C 21
#define THRESH 0.5f
#define ALPHA 10.0f

// ---------------- k1: best prior per object (obj_idx) -----------------------
// one wave per (b, m); lanes stride priors; argmax with first-index tie-break
__global__ __launch_bounds__(256) void k1_objargmax(
    const float* __restrict__ b_boxes, const float* __restrict__ priors,
    int* __restrict__ objidx) {
  int wid = threadIdx.x >> 6;
  int lane = threadIdx.x & 63;
  int task = blockIdx.x * 4 + wid;  // (b*M + m)
  if (task >= B * M) return;
  const float* bx = b_boxes + (size_t)task * 4;
  float x1 = bx[0], y1 = bx[1], x2 = bx[2], y2 = bx[3];
  float areaA = (x2 - x1) * (y2 - y1);
  float best = -1.0f;
  int bi = P;
  for (int p = lane; p < P; p += 64) {
    float4 pr = ((const float4*)priors)[p];
    float pw2 = pr.z * 0.5f, ph2 = pr.w * 0.5f;
    float iw = fminf(x2, pr.x + pw2) - fmaxf(x1, pr.x - pw2);
    float ih = fminf(y2, pr.y + ph2) - fmaxf(y1, pr.y - ph2);
    iw = fmaxf(iw, 0.0f);
    ih = fmaxf(ih, 0.0f);
    float inter = iw * ih;
    float iou = inter / (areaA + pr.z * pr.w - inter);
    if (iou > best) { best = iou; bi = p; }  // strict > keeps smallest p
  }
  for (int off = 32; off >= 1; off >>= 1) {
    float ov = __shfl_xor(best, off, 64);
    int oi = __shfl_xor(bi, off, 64);
    if (ov > best || (ov == best && oi < bi)) { best = ov; bi = oi; }
  }
  if (lane == 0) objidx[task] = bi;
}

// ---------------- k2: per-prior match + loc partial + CE --------------------
__global__ __launch_bounds__(256) void k2_perprior(
    const float* __restrict__ pred_loc, const float* __restrict__ pred_cls,
    const float* __restrict__ b_boxes, const int* __restrict__ b_labels,
    const float* __restrict__ priors, const int* __restrict__ objidx,
    float* __restrict__ acc, int* __restrict__ nposimg,
    float* __restrict__ confneg) {
  int b = blockIdx.y;
  __shared__ float sx1[M], sy1[M], sx2[M], sy2[M], sarea[M];
  __shared__ int slab[M], sobj[M];
  if (threadIdx.x < M) {
    int m = threadIdx.x;
    float4 bx = ((const float4*)b_boxes)[b * M + m];
    sx1[m] = bx.x; sy1[m] = bx.y; sx2[m] = bx.z; sy2[m] = bx.w;
    sarea[m] = (bx.z - bx.x) * (bx.w - bx.y);
    slab[m] = b_labels[b * M + m];
    sobj[m] = objidx[b * M + m];
  }
  __syncthreads();

  int p = blockIdx.x * 256 + threadIdx.x;
  float locpart = 0.0f, cepospart = 0.0f;
  int npos = 0;
  if (p < P) {
    float4 pr = ((const float4*)priors)[p];
    float pw2 = pr.z * 0.5f, ph2 = pr.w * 0.5f;
    float px1 = pr.x - pw2, py1 = pr.y - ph2;
    float px2 = pr.x + pw2, py2 = pr.y + ph2;
    float areaP = pr.z * pr.w;
    float best = -1.0f;
    int bm = 0;
#pragma unroll
    for (int m = 0; m < M; m++) {
      float iw = fminf(sx2[m], px2) - fmaxf(sx1[m], px1);
      float ih = fminf(sy2[m], py2) - fmaxf(sy1[m], py1);
      iw = fmaxf(iw, 0.0f);
      ih = fmaxf(ih, 0.0f);
      float inter = iw * ih;
      float iou = inter / (sarea[m] + areaP - inter);
      if (sobj[m] == p) iou = 1.0f;        // forced best-prior-per-object
      if (iou > best) { best = iou; bm = m; }  // first max (ascending m)
    }
    bool pos = best >= THRESH;
    int cls = pos ? slab[bm] : 0;

    // encode matched box vs prior
    float bx1 = sx1[bm], by1 = sy1[bm], bx2 = sx2[bm], by2 = sy2[bm];
    float cx = (bx1 + bx2) * 0.5f, cy = (by1 + by2) * 0.5f;
    float w = bx2 - bx1, h = by2 - by1;
    float g0 = (cx - pr.x) * 10.0f / pr.z;
    float g1 = (cy - pr.y) * 10.0f / pr.w;
    float g2 = logf(w / pr.z) * 5.0f;
    float g3 = logf(h / pr.w) * 5.0f;

    float4 pl = ((const float4*)pred_loc)[(size_t)b * P + p];
    if (pos) {
      locpart = fabsf(pl.x - g0) + fabsf(pl.y - g1) +
                fabsf(pl.z - g2) + fabsf(pl.w - g3);
      npos = 1;
    }

    // cross-entropy via stabilized logsumexp over 21 classes
    const float* pc = pred_cls + ((size_t)b * P + p) * C;
    float v[C];
#pragma unroll
    for (int c = 0; c < C; c++) v[c] = pc[c];
    float mx = v[0];
#pragma unroll
    for (int c = 1; c < C; c++) mx = fmaxf(mx, v[c]);
    float se = 0.0f;
#pragma unroll
    for (int c = 0; c < C; c++) se += expf(v[c] - mx);
    float lse = mx + logf(se);
    float ce = lse - v[cls];

    confneg[(size_t)b * P + p] = pos ? 0.0f : ce;
    cepospart = pos ? ce : 0.0f;
  }

  // block reduction -> global atomics
  for (int off = 32; off >= 1; off >>= 1) {
    locpart += __shfl_down(locpart, off, 64);
    cepospart += __shfl_down(cepospart, off, 64);
    npos += __shfl_down(npos, off, 64);
  }
  __shared__ float rloc[4], rce[4];
  __shared__ int rnp[4];
  int wid = threadIdx.x >> 6;
  if ((threadIdx.x & 63) == 0) { rloc[wid] = locpart; rce[wid] = cepospart; rnp[wid] = npos; }
  __syncthreads();
  if (threadIdx.x == 0) {
    float l = rloc[0] + rloc[1] + rloc[2] + rloc[3];
    float ce = rce[0] + rce[1] + rce[2] + rce[3];
    int n = rnp[0] + rnp[1] + rnp[2] + rnp[3];
    atomicAdd(&acc[0], l);
    atomicAdd(&acc[1], ce);
    if (n) atomicAdd(&nposimg[b], n);
  }
}

// ---------------- k3: per-image exact top-K sum of conf_neg -----------------
// K-th largest via bitwise binary search on IEEE bits (all values >= 0).
__global__ __launch_bounds__(256) void k3_hardneg(
    const float* __restrict__ confneg, const int* __restrict__ nposimg,
    float* __restrict__ acc) {
  int b = blockIdx.x;
  __shared__ float s[P];
  __shared__ int scnt;
  __shared__ float rsum[4];
  __shared__ int rcnt[4];
  const float* row = confneg + (size_t)b * P;
  for (int i = threadIdx.x; i < P; i += 256) s[i] = row[i];
  int K = nposimg[b] * 3;
  if (K > P) K = P;
  __syncthreads();

  unsigned u = 0;
  for (int bit = 30; bit >= 0; --bit) {
    unsigned trial = u | (1u << bit);
    float t = __uint_as_float(trial);
    if (threadIdx.x == 0) scnt = 0;
    __syncthreads();
    int cnt = 0;
    for (int i = threadIdx.x; i < P; i += 256) cnt += (s[i] >= t) ? 1 : 0;
    for (int off = 32; off >= 1; off >>= 1) cnt += __shfl_down(cnt, off, 64);
    if ((threadIdx.x & 63) == 0) atomicAdd(&scnt, cnt);
    __syncthreads();
    if (scnt >= K) u = trial;  // uniform across block
    __syncthreads();
  }
  float t = __uint_as_float(u);  // K-th largest value (tau)

  float sum = 0.0f;
  int cgt = 0;
  for (int i = threadIdx.x; i < P; i += 256) {
    float v = s[i];
    if (v > t) { sum += v; cgt++; }
  }
  for (int off = 32; off >= 1; off >>= 1) {
    sum += __shfl_down(sum, off, 64);
    cgt += __shfl_down(cgt, off, 64);
  }
  int wid = threadIdx.x >> 6;
  if ((threadIdx.x & 63) == 0) { rsum[wid] = sum; rcnt[wid] = cgt; }
  __syncthreads();
  if (threadIdx.x == 0) {
    float stot = rsum[0] + rsum[1] + rsum[2] + rsum[3];
    int ctot = rcnt[0] + rcnt[1] + rcnt[2] + rcnt[3];
    float hard = stot + (float)(K - ctot) * t;  // ties at tau handled exactly
    atomicAdd(&acc[2], hard);
  }
}

// ---------------- k4: finalize --------------------------------------------
__global__ void k4_final(const float* __restrict__ acc,
                         const int* __restrict__ nposimg,
                         float* __restrict__ out) {
  if (threadIdx.x == 0) {
    int n = 0;
    for (int i = 0; i < B; i++) n += nposimg[i];
    float nf = (float)n;
    float loc = ALPHA * acc[0] / (nf * 4.0f);
    float conf = (acc[2] + acc[1]) / nf;
    out[0] = conf + loc;
    out[1] = loc;
    out[2] = conf;
  }
}

extern "C" void kernel_launch(void* const* d_in, const int* in_sizes, int n_in,
                              void* d_out, int out_size, void* d_ws, size_t ws_size,
                              hipStream_t stream) {
  (void)in_sizes; (void)n_in; (void)out_size; (void)ws_size;
  const float* pred_loc = (const float*)d_in[0];
  const float* pred_cls = (const float*)d_in[1];
  const float* b_boxes = (const float*)d_in[2];
  const int* b_labels = (const int*)d_in[3];
  const float* priors = (const float*)d_in[4];
  float* out = (float*)d_out;

  // workspace layout
  float* acc = (float*)d_ws;               // [0]=loc_sum [1]=ce_pos [2]=hard_neg
  int* nposimg = (int*)d_ws + 8;           // B ints
  int* objidx = (int*)d_ws + 8 + B;        // B*M ints
  float* confneg = (float*)d_ws + 8 + B + B * M;  // B*P floats

  hipMemsetAsync(d_ws, 0, (8 + B) * sizeof(float), stream);

  k1_objargmax<<<(B * M + 3) / 4, 256, 0, stream>>>(b_boxes, priors, objidx);
  dim3 g2((P + 255) / 256, B);
  k2_perprior<<<g2, 256, 0, stream>>>(pred_loc, pred_cls, b_boxes, b_labels,
                                      priors, objidx, acc, nposimg, confneg);
  k3_hardneg<<<B, 256, 0, stream>>>(confneg, nposimg, acc);
  k4_final<<<1, 64, 0, stream>>>(acc, nposimg, out);
}